// Round 3
// baseline (52717.700 us; speedup 1.0000x reference)
//
#include <hip/hip_runtime.h>
#include <math.h>

#define T_STEPS 2048
#define BATCH   64
#define IDIM    256
#define HDIM    512
#define K1      768
#define H3      1536
#define NGROUP  4
#define NSLICE  32
#define RPG     16
#define THREADS 512

// ---------------------------------------------------------------------------
// Round-3: round-0 agent-scope protocol, restructured to 3 syncs/step.
//   - cb (c broadcast) sync ELIMINATED: at the stage-3 sync, producers
//     broadcast raw o_c / o_f slices (f32) + LN3 partial stats; every block
//     redundantly reconstructs c for all 512 cols of its group's rows
//     (c_old kept in f32 registers) and writes bf16 c directly into the zh
//     K-region for next step's GEMM1. Deterministic: identical f32 inputs,
//     identical arithmetic order in every block.
//   - stamps -> monotonic per-group counters: producing waves fetch_add
//     after their own vmcnt(0) drain (no publish __syncthreads); consumers
//     poll ONE dword (>= waves_per_sync * (t+1)).
//   Buffer reuse safety (single-buffered a1/a2/oc/of/p3): block X reads
//   step-t data before X's next counter add, which transitively gates every
//   step-t+1 writer (same chain as round-0).
// ---------------------------------------------------------------------------

// dword-unit workspace offsets
#define OFF_A1 0            // 64*512 f32
#define OFF_A2 32768        // 64*512 f32
#define OFF_OC 65536        // 64*512 f32 (raw o_c broadcast)
#define OFF_OF 98304        // 64*512 f32 (raw o_f broadcast)
#define OFF_P3 131072       // 64 rows * 32 slices * 2 f32
#define OFF_CT 135168       // 4 groups * 3 counters * 64-int stride
#define N_CT   768

typedef __attribute__((ext_vector_type(8))) __bf16 bf16x8;
typedef __attribute__((ext_vector_type(4))) float f32x4;

__device__ __forceinline__ f32x4 MFMA(bf16x8 a, bf16x8 b, f32x4 c) {
    return __builtin_amdgcn_mfma_f32_16x16x32_bf16(a, b, c, 0, 0, 0);
}

__device__ __forceinline__ float2 gload2(const float* p) {
    unsigned long long v = __hip_atomic_load((const unsigned long long*)p,
                                             __ATOMIC_RELAXED, __HIP_MEMORY_SCOPE_AGENT);
    return __builtin_bit_cast(float2, v);
}
__device__ __forceinline__ void gstore2(float* p, float a, float b) {
    float2 v = {a, b};
    __hip_atomic_store((unsigned long long*)p, __builtin_bit_cast(unsigned long long, v),
                       __ATOMIC_RELAXED, __HIP_MEMORY_SCOPE_AGENT);
}
__device__ __forceinline__ int gload_i(const int* p) {
    return __hip_atomic_load(p, __ATOMIC_RELAXED, __HIP_MEMORY_SCOPE_AGENT);
}

struct bf16pair { __bf16 hi, lo; };
__device__ __forceinline__ bf16pair split2(float f) {
    bf16pair r;
    r.hi = (__bf16)f;
    r.lo = (__bf16)(f - (float)r.hi);
    return r;
}
__device__ __forceinline__ unsigned pk2(float a, float b) {
    return (unsigned)__builtin_bit_cast(unsigned short, (__bf16)a) |
           ((unsigned)__builtin_bit_cast(unsigned short, (__bf16)b) << 16);
}
__device__ __forceinline__ void st_pair(__bf16* p, __bf16 a, __bf16 b) {
    unsigned v = (unsigned)__builtin_bit_cast(unsigned short, a) |
                 ((unsigned)__builtin_bit_cast(unsigned short, b) << 16);
    *(unsigned*)p = v;
}
__device__ __forceinline__ float elu1(float v) {
    return v > 0.f ? v : (expf(v) - 1.f);
}

// Producing wave: drain own stores, lane0 bumps the group counter.
__device__ __forceinline__ void wave_pub(int* c) {
    asm volatile("s_waitcnt vmcnt(0)" ::: "memory");
    if ((threadIdx.x & 63) == 0)
        (void)__hip_atomic_fetch_add(c, 1, __ATOMIC_RELAXED, __HIP_MEMORY_SCOPE_AGENT);
}
__device__ __forceinline__ void poll_ctr(const int* c, int tgt) {
    while (gload_i(c) < tgt) __builtin_amdgcn_s_sleep(1);
}

__global__ void dlstm_init(float* __restrict__ ws) {
    int idx = threadIdx.x;
    if (idx < N_CT) ((int*)ws + OFF_CT)[idx] = 0;
}

__global__ __launch_bounds__(THREADS, 2) void dlstm_main(
    const float* __restrict__ x,
    const float* __restrict__ W1, const float* __restrict__ g1, const float* __restrict__ b1,
    const float* __restrict__ W2, const float* __restrict__ g2, const float* __restrict__ b2,
    const float* __restrict__ W3, const float* __restrict__ g3, const float* __restrict__ b3,
    float* __restrict__ out, float* __restrict__ ws)
{
    const int tid = threadIdx.x;
    const int bid = blockIdx.x;
    const int g = bid & 3;
    const int s = bid >> 2;          // 0..31 feature slice
    const int r0 = g * RPG;

    const int lane = tid & 63;
    const int wv   = tid >> 6;       // wave 0..7 (k-split)
    const int col  = lane & 15;
    const int kq   = lane >> 4;
    const int er   = tid >> 5;       // row 0..15 for elementwise phases
    const int l32  = tid & 31;

    float* a1    = ws + OFF_A1;
    float* a2    = ws + OFF_A2;
    float* oc_ws = ws + OFF_OC;
    float* of_ws = ws + OFF_OF;
    float* p3    = ws + OFF_P3;
    int*   ctb   = (int*)ws + OFF_CT + g * 192;
    int*   ctA   = ctb;
    int*   ctB   = ctb + 64;
    int*   ctC   = ctb + 128;

    __shared__ __bf16 zh[16][776];   // 388 dwords/row, 388%32==4
    __shared__ float comb[8][3][256];
    __shared__ float slab[16][48];   // raw o: [i|16+i|32+i] = h,c,f gates
    __shared__ float stats[16][2];
    __shared__ float g3c_s[512], b3c_s[512], g3f_s[512], b3f_s[512];

    // LN3 c/f params -> LDS (read per-col in the reconstruct pass)
    {
        g3c_s[tid] = g3[HDIM + tid];     b3c_s[tid] = b3[HDIM + tid];
        g3f_s[tid] = g3[2 * HDIM + tid]; b3f_s[tid] = b3[2 * HDIM + tid];
    }

    // ---------------- hoisted LN params (loop-invariant) ----------------
    float2 g1v[8], b1v[8], g2v[8], b2v[8];
    #pragma unroll
    for (int j = 0; j < 8; ++j) {
        int k = j * 64 + l32 * 2;
        g1v[j] = *(const float2*)(g1 + k); b1v[j] = *(const float2*)(b1 + k);
        g2v[j] = *(const float2*)(g2 + k); b2v[j] = *(const float2*)(b2 + k);
    }
    float g3h = 0.f, b3h = 0.f;
    if (tid < 256) {
        int i = tid & 15;
        g3h = g3[16 * s + i]; b3h = b3[16 * s + i];
    }

    // ---------------- weights -> register fragments (hi/lo split) ----------------
    bf16x8 w1h[3], w1l[3], w2h[2], w2l[2], w3h[3][2], w3l[3][2];
    #pragma unroll
    for (int ks = 0; ks < 3; ++ks) {
        int k0 = wv * 96 + ks * 32 + kq * 8;
        const float* p = W1 + (size_t)(16 * s + col) * K1 + k0;
        #pragma unroll
        for (int e = 0; e < 8; ++e) {
            bf16pair pr = split2(p[e]);
            w1h[ks][e] = pr.hi; w1l[ks][e] = pr.lo;
        }
    }
    #pragma unroll
    for (int ks = 0; ks < 2; ++ks) {
        int k0 = wv * 64 + ks * 32 + kq * 8;
        const float* p = W2 + (size_t)(16 * s + col) * HDIM + k0;
        #pragma unroll
        for (int e = 0; e < 8; ++e) {
            bf16pair pr = split2(p[e]);
            w2h[ks][e] = pr.hi; w2l[ks][e] = pr.lo;
        }
    }
    #pragma unroll
    for (int tb = 0; tb < 3; ++tb) {
        #pragma unroll
        for (int ks = 0; ks < 2; ++ks) {
            int k0 = wv * 64 + ks * 32 + kq * 8;
            const float* p = W3 + (size_t)(tb * HDIM + 16 * s + col) * HDIM + k0;
            #pragma unroll
            for (int e = 0; e < 8; ++e) {
                bf16pair pr = split2(p[e]);
                w3h[tb][ks][e] = pr.hi; w3l[tb][ks][e] = pr.lo;
            }
        }
    }

    // Reconstructed cell state: thread (er, l32) owns cols {2*l32+64k, +1}
    // of row r0+er, kept in f32 (better than round-0's bf16 broadcast).
    float cr[8][2];
    #pragma unroll
    for (int k = 0; k < 8; ++k) { cr[k][0] = 0.f; cr[k][1] = 0.f; }
    // zero the zh c-region for t=0 (dword 128 + l32 + 32k of row er)
    #pragma unroll
    for (int k = 0; k < 8; ++k)
        st_pair(&zh[er][256 + 2 * l32 + 64 * k], (__bf16)0.f, (__bf16)0.f);

    // prefetch + pre-pack x for t=0
    float2 xr[4];
    unsigned xb[4];
    {
        const float* xrow = x + (size_t)(r0 + er) * IDIM;
        #pragma unroll
        for (int j = 0; j < 4; ++j) xr[j] = *(const float2*)(xrow + j * 64 + l32 * 2);
        #pragma unroll
        for (int j = 0; j < 4; ++j) xb[j] = pk2(xr[j].x, xr[j].y);
    }

    #pragma unroll 1
    for (int t = 0; t < T_STEPS; ++t) {
        unsigned* zrow = (unsigned*)&zh[er][0];
        // ================= stage 1: x-plane; full GEMM1 (c already in zh) =================
        #pragma unroll
        for (int j = 0; j < 4; ++j) zrow[j * 32 + l32] = xb[j];
        __syncthreads();                                              // b1
        {
            f32x4 acc = {0.f, 0.f, 0.f, 0.f};
            #pragma unroll
            for (int ks = 0; ks < 3; ++ks) {
                bf16x8 ah = *(const bf16x8*)&zh[col][wv * 96 + ks * 32 + kq * 8];
                acc = MFMA(ah, w1h[ks], acc);
                acc = MFMA(ah, w1l[ks], acc);
            }
            #pragma unroll
            for (int i = 0; i < 4; ++i) comb[wv][0][(kq * 4 + i) * 16 + col] = acc[i];
        }
        __syncthreads();                                              // b2
        if (tid < 128) {             // waves 0,1 exactly
            int r = tid >> 3, fp = tid & 7;
            int i0 = r * 16 + fp * 2;
            float v0 = 0.f, v1 = 0.f;
            #pragma unroll
            for (int w = 0; w < 8; ++w) { v0 += comb[w][0][i0]; v1 += comb[w][0][i0 + 1]; }
            gstore2(&a1[(size_t)(r0 + r) * HDIM + 16 * s + fp * 2], v0, v1);
            wave_pub(ctA);           // +2 per block -> target 64*(t+1)
        }

        // ================= stage 2: h1 = elu(LN(a1)); GEMM2 =================
        poll_ctr(ctA, 64 * (t + 1));
        {
            size_t arow = (size_t)(r0 + er) * HDIM;
            float2 va[8]; float s1 = 0.f, s2 = 0.f;
            #pragma unroll
            for (int j = 0; j < 8; ++j) {
                va[j] = gload2(a1 + arow + j * 64 + l32 * 2);
                s1 += va[j].x + va[j].y; s2 += va[j].x * va[j].x + va[j].y * va[j].y;
            }
            s1 += __shfl_xor(s1, 1, 64); s2 += __shfl_xor(s2, 1, 64);
            s1 += __shfl_xor(s1, 2, 64); s2 += __shfl_xor(s2, 2, 64);
            s1 += __shfl_xor(s1, 4, 64); s2 += __shfl_xor(s2, 4, 64);
            s1 += __shfl_xor(s1, 8, 64); s2 += __shfl_xor(s2, 8, 64);
            s1 += __shfl_xor(s1, 16, 64); s2 += __shfl_xor(s2, 16, 64);
            float mu = s1 * (1.f / HDIM);
            float var = s2 * (1.f / HDIM) - mu * mu;
            float rs = rsqrtf(var + 1e-5f);
            #pragma unroll
            for (int j = 0; j < 8; ++j) {
                int k = j * 64 + l32 * 2;
                float v0 = elu1((va[j].x - mu) * rs * g1v[j].x + b1v[j].x);
                float v1 = elu1((va[j].y - mu) * rs * g1v[j].y + b1v[j].y);
                st_pair(&zh[er][k], (__bf16)v0, (__bf16)v1);
            }
        }
        __syncthreads();                                              // b3
        {
            f32x4 acc2 = {0.f, 0.f, 0.f, 0.f};
            #pragma unroll
            for (int ks = 0; ks < 2; ++ks) {
                int k0 = wv * 64 + ks * 32 + kq * 8;
                bf16x8 ah = *(const bf16x8*)&zh[col][k0];
                acc2 = MFMA(ah, w2h[ks], acc2);
                acc2 = MFMA(ah, w2l[ks], acc2);
            }
            #pragma unroll
            for (int i = 0; i < 4; ++i) comb[wv][0][(kq * 4 + i) * 16 + col] = acc2[i];
        }
        __syncthreads();                                              // b4
        if (tid < 128) {
            int r = tid >> 3, fp = tid & 7;
            int i0 = r * 16 + fp * 2;
            float v0 = 0.f, v1 = 0.f;
            #pragma unroll
            for (int w = 0; w < 8; ++w) { v0 += comb[w][0][i0]; v1 += comb[w][0][i0 + 1]; }
            gstore2(&a2[(size_t)(r0 + r) * HDIM + 16 * s + fp * 2], v0, v1);
            wave_pub(ctB);           // target 64*(t+1)
        }

        // ================= stage 3: h2 = elu(LN(a2)); prefetch x(t+1); GEMM3 =================
        poll_ctr(ctB, 64 * (t + 1));
        {
            {   // prefetch next x while a2 loads are in flight
                int tn = (t + 1 < T_STEPS) ? t + 1 : t;
                const float* xrow = x + ((size_t)tn * BATCH + r0 + er) * IDIM;
                #pragma unroll
                for (int j = 0; j < 4; ++j) xr[j] = *(const float2*)(xrow + j * 64 + l32 * 2);
            }
            size_t arow = (size_t)(r0 + er) * HDIM;
            float2 va[8]; float s1 = 0.f, s2 = 0.f;
            #pragma unroll
            for (int j = 0; j < 8; ++j) va[j] = gload2(a2 + arow + j * 64 + l32 * 2);
            #pragma unroll
            for (int j = 0; j < 8; ++j) {
                s1 += va[j].x + va[j].y; s2 += va[j].x * va[j].x + va[j].y * va[j].y;
            }
            s1 += __shfl_xor(s1, 1, 64); s2 += __shfl_xor(s2, 1, 64);
            s1 += __shfl_xor(s1, 2, 64); s2 += __shfl_xor(s2, 2, 64);
            s1 += __shfl_xor(s1, 4, 64); s2 += __shfl_xor(s2, 4, 64);
            s1 += __shfl_xor(s1, 8, 64); s2 += __shfl_xor(s2, 8, 64);
            s1 += __shfl_xor(s1, 16, 64); s2 += __shfl_xor(s2, 16, 64);
            float mu = s1 * (1.f / HDIM);
            float var = s2 * (1.f / HDIM) - mu * mu;
            float rs = rsqrtf(var + 1e-5f);
            #pragma unroll
            for (int j = 0; j < 8; ++j) {
                int k = j * 64 + l32 * 2;
                float v0 = elu1((va[j].x - mu) * rs * g2v[j].x + b2v[j].x);
                float v1 = elu1((va[j].y - mu) * rs * g2v[j].y + b2v[j].y);
                st_pair(&zh[er][k], (__bf16)v0, (__bf16)v1);
            }
        }
        __syncthreads();                                              // b5
        {
            f32x4 acc0 = {0.f,0.f,0.f,0.f}, acc1 = {0.f,0.f,0.f,0.f}, acc2 = {0.f,0.f,0.f,0.f};
            #pragma unroll
            for (int ks = 0; ks < 2; ++ks) {
                int k0 = wv * 64 + ks * 32 + kq * 8;
                bf16x8 ah = *(const bf16x8*)&zh[col][k0];
                acc0 = MFMA(ah, w3h[0][ks], acc0);
                acc0 = MFMA(ah, w3l[0][ks], acc0);
                acc1 = MFMA(ah, w3h[1][ks], acc1);
                acc1 = MFMA(ah, w3l[1][ks], acc1);
                acc2 = MFMA(ah, w3h[2][ks], acc2);
                acc2 = MFMA(ah, w3l[2][ks], acc2);
            }
            #pragma unroll
            for (int i = 0; i < 4; ++i) {
                comb[wv][0][(kq * 4 + i) * 16 + col] = acc0[i];
                comb[wv][1][(kq * 4 + i) * 16 + col] = acc1[i];
                comb[wv][2][(kq * 4 + i) * 16 + col] = acc2[i];
            }
        }
        __syncthreads();                                              // b6
        if (tid < 384) {             // reduce; broadcast raw o_c / o_f slices
            int o = tid * 2;
            int tb = o >> 8, idx = o & 255;
            int r = idx >> 4, f0 = idx & 15;
            float v0 = 0.f, v1 = 0.f;
            #pragma unroll
            for (int w = 0; w < 8; ++w) { v0 += comb[w][tb][idx]; v1 += comb[w][tb][idx + 1]; }
            slab[r][tb * 16 + f0]     = v0;
            slab[r][tb * 16 + f0 + 1] = v1;
            if (tb == 1)
                gstore2(&oc_ws[(size_t)(r0 + r) * HDIM + 16 * s + f0], v0, v1);
            else if (tb == 2)
                gstore2(&of_ws[(size_t)(r0 + r) * HDIM + 16 * s + f0], v0, v1);
        }
        __syncthreads();                                              // b7
        {
            float va_ = slab[er][l32];
            float vb_ = (l32 < 16) ? slab[er][32 + l32] : 0.f;
            float s1 = va_ + vb_;
            float s2 = va_ * va_ + vb_ * vb_;
            s1 += __shfl_xor(s1, 1, 64); s2 += __shfl_xor(s2, 1, 64);
            s1 += __shfl_xor(s1, 2, 64); s2 += __shfl_xor(s2, 2, 64);
            s1 += __shfl_xor(s1, 4, 64); s2 += __shfl_xor(s2, 4, 64);
            s1 += __shfl_xor(s1, 8, 64); s2 += __shfl_xor(s2, 8, 64);
            s1 += __shfl_xor(s1, 16, 64); s2 += __shfl_xor(s2, 16, 64);
            if (l32 == 0) gstore2(&p3[((size_t)(r0 + er) * NSLICE + s) * 2], s1, s2);
        }
        wave_pub(ctC);               // all 8 waves -> target 256*(t+1)

        // ================= epilogue: LN3 stats; reconstruct full c locally =================
        poll_ctr(ctC, 256 * (t + 1));
        // issue o_c / o_f gathers first (overlap with the stats reduce)
        float2 ocv[8], ofv[8];
        {
            const float* ocr = oc_ws + (size_t)(r0 + er) * HDIM + 2 * l32;
            const float* ofr = of_ws + (size_t)(r0 + er) * HDIM + 2 * l32;
            #pragma unroll
            for (int k = 0; k < 8; ++k) {
                ocv[k] = gload2(ocr + 64 * k);
                ofv[k] = gload2(ofr + 64 * k);
            }
        }
        {
            float2 pv = gload2(&p3[((size_t)(r0 + er) * NSLICE + l32) * 2]);
            float s1 = pv.x, s2 = pv.y;
            s1 += __shfl_xor(s1, 1, 64); s2 += __shfl_xor(s2, 1, 64);
            s1 += __shfl_xor(s1, 2, 64); s2 += __shfl_xor(s2, 2, 64);
            s1 += __shfl_xor(s1, 4, 64); s2 += __shfl_xor(s2, 4, 64);
            s1 += __shfl_xor(s1, 8, 64); s2 += __shfl_xor(s2, 8, 64);
            s1 += __shfl_xor(s1, 16, 64); s2 += __shfl_xor(s2, 16, 64);
            float mu = s1 * (1.f / H3);
            float var = s2 * (1.f / H3) - mu * mu;
            float rs = rsqrtf(var + 1e-5f);
            if (l32 == 0) { stats[er][0] = mu; stats[er][1] = rs; }
        }
        __syncthreads();                                              // b8
        {
            float mu = stats[er][0], rs = stats[er][1];
            #pragma unroll
            for (int k = 0; k < 8; ++k) {
                int c0k = 2 * l32 + 64 * k;
                float2 gc = *(const float2*)&g3c_s[c0k];
                float2 bc = *(const float2*)&b3c_s[c0k];
                float2 gf = *(const float2*)&g3f_s[c0k];
                float2 bf = *(const float2*)&b3f_s[c0k];
                float ocn0 = (ocv[k].x - mu) * rs * gc.x + bc.x;
                float ocn1 = (ocv[k].y - mu) * rs * gc.y + bc.y;
                float ofn0 = (ofv[k].x - mu) * rs * gf.x + bf.x;
                float ofn1 = (ofv[k].y - mu) * rs * gf.y + bf.y;
                float sg0 = 1.f / (1.f + expf(-ofn0)); float f0 = sg0 * sg0;
                float sg1 = 1.f / (1.f + expf(-ofn1)); float f1 = sg1 * sg1;
                float cn0 = f0 * elu1(ocn0) + (1.f - f0) * cr[k][0];
                float cn1 = f1 * elu1(ocn1) + (1.f - f1) * cr[k][1];
                cr[k][0] = cn0; cr[k][1] = cn1;
                st_pair(&zh[er][256 + c0k], (__bf16)cn0, (__bf16)cn1);
                if (t == T_STEPS - 1) {
                    float2 cf = {cn0, cn1};   // same value from every slice: benign
                    *(float2*)(out + (size_t)T_STEPS * BATCH * HDIM
                                   + (size_t)(r0 + er) * HDIM + c0k) = cf;
                }
            }
        }
        if (tid < 256) {             // own-slice h output
            int r = tid >> 4, i = tid & 15;
            float mu = stats[r][0], rs = stats[r][1];
            float oh = (slab[r][i] - mu) * rs * g3h + b3h;
            out[((size_t)t * BATCH + r0 + r) * HDIM + 16 * s + i] = elu1(oh);
        }
        // pack next-step x (loads issued in stage 3 are long since complete)
        #pragma unroll
        for (int j = 0; j < 4; ++j) xb[j] = pk2(xr[j].x, xr[j].y);
        // next stage-1's b1 orders zh c-writes/x-writes before the MFMA reads
    }
}

extern "C" void kernel_launch(void* const* d_in, const int* in_sizes, int n_in,
                              void* d_out, int out_size, void* d_ws, size_t ws_size,
                              hipStream_t stream) {
    const float* x  = (const float*)d_in[0];
    const float* W1 = (const float*)d_in[1];
    const float* g1 = (const float*)d_in[2];
    const float* b1 = (const float*)d_in[3];
    const float* W2 = (const float*)d_in[4];
    const float* g2 = (const float*)d_in[5];
    const float* b2 = (const float*)d_in[6];
    const float* W3 = (const float*)d_in[7];
    const float* g3 = (const float*)d_in[8];
    const float* b3 = (const float*)d_in[9];
    float* out = (float*)d_out;
    float* ws  = (float*)d_ws;

    dlstm_init<<<1, 768, 0, stream>>>(ws);
    dlstm_main<<<NGROUP * NSLICE, THREADS, 0, stream>>>(x, W1, g1, b1, W2, g2, b2, W3, g3, b3, out, ws);
}

// Round 4
// 28278.586 us; speedup vs baseline: 1.8642x; 1.8642x over previous
//
#include <hip/hip_runtime.h>
#include <math.h>

#define T_STEPS 2048
#define BATCH   64
#define IDIM    256
#define HDIM    512
#define K1      768
#define H3      1536
#define NGROUP  4
#define NSLICE  32
#define RPG     16
#define THREADS 512

// ---------------------------------------------------------------------------
// Round-4 = round-3's verified 3-sync dataflow + round-0's proven stamp
// protocol (per-slice stamp STORES, 32-line wave polling — NO atomic RMW) +
// two latency hidings:
//   * GEMM1-x hoisted into the p3 sync window (x(t+1) written to zh in the
//     B9->B10 window after GEMM3 is done; acc carried across the loop).
//   * h out-stores issued before the c-reconstruct so their drain overlaps.
// Syncs/step: a1, a2, p3 (cb eliminated: every block reconstructs c for all
// 512 cols of its group's rows from the broadcast raw o_c/o_f + LN3 stats;
// identical f32 inputs + identical order in every block => identical c).
// ---------------------------------------------------------------------------

// dword-unit workspace offsets
#define OFF_A1 0            // 64*512 f32
#define OFF_A2 32768        // 64*512 f32
#define OFF_OC 65536        // 64*512 f32 (raw o_c broadcast)
#define OFF_OF 98304        // 64*512 f32 (raw o_f broadcast)
#define OFF_P3 131072       // 64 rows * 32 slices * 2 f32
#define OFF_ST 135168       // 3 stages * 4 groups * 32 stamps = 384 ints
#define N_ST   384

typedef __attribute__((ext_vector_type(8))) __bf16 bf16x8;
typedef __attribute__((ext_vector_type(4))) float f32x4;

__device__ __forceinline__ f32x4 MFMA(bf16x8 a, bf16x8 b, f32x4 c) {
    return __builtin_amdgcn_mfma_f32_16x16x32_bf16(a, b, c, 0, 0, 0);
}

__device__ __forceinline__ float2 gload2(const float* p) {
    unsigned long long v = __hip_atomic_load((const unsigned long long*)p,
                                             __ATOMIC_RELAXED, __HIP_MEMORY_SCOPE_AGENT);
    return __builtin_bit_cast(float2, v);
}
__device__ __forceinline__ void gstore2(float* p, float a, float b) {
    float2 v = {a, b};
    __hip_atomic_store((unsigned long long*)p, __builtin_bit_cast(unsigned long long, v),
                       __ATOMIC_RELAXED, __HIP_MEMORY_SCOPE_AGENT);
}
__device__ __forceinline__ int gload_i(const int* p) {
    return __hip_atomic_load(p, __ATOMIC_RELAXED, __HIP_MEMORY_SCOPE_AGENT);
}

struct bf16pair { __bf16 hi, lo; };
__device__ __forceinline__ bf16pair split2(float f) {
    bf16pair r;
    r.hi = (__bf16)f;
    r.lo = (__bf16)(f - (float)r.hi);
    return r;
}
__device__ __forceinline__ unsigned pk2(float a, float b) {
    return (unsigned)__builtin_bit_cast(unsigned short, (__bf16)a) |
           ((unsigned)__builtin_bit_cast(unsigned short, (__bf16)b) << 16);
}
__device__ __forceinline__ void st_pair(__bf16* p, __bf16 a, __bf16 b) {
    unsigned v = (unsigned)__builtin_bit_cast(unsigned short, a) |
                 ((unsigned)__builtin_bit_cast(unsigned short, b) << 16);
    *(unsigned*)p = v;
}
__device__ __forceinline__ float elu1(float v) {
    return v > 0.f ? v : (expf(v) - 1.f);
}

// Producer publish: data stores -> __syncthreads (drains every thread's
// vmcnt; agent-scope stores are LLC-visible) -> one stamp store.
__device__ __forceinline__ void publish(int* stamp_s, int val) {
    __syncthreads();
    if (threadIdx.x == 0)
        __hip_atomic_store(stamp_s, val, __ATOMIC_RELAXED, __HIP_MEMORY_SCOPE_AGENT);
}
// Every wave polls all 32 slice stamps independently (lane&31 -> stamp).
__device__ __forceinline__ void poll_wave(const int* st, int target) {
    const int* p = st + (threadIdx.x & 31);
    while (true) {
        int v = gload_i(p);
        if (__all(v >= target)) break;
        __builtin_amdgcn_s_sleep(1);
    }
}

__global__ void dlstm_init(float* __restrict__ ws) {
    int idx = threadIdx.x;
    if (idx < N_ST) ((int*)ws + OFF_ST)[idx] = 0;
}

__global__ __launch_bounds__(THREADS, 2) void dlstm_main(
    const float* __restrict__ x,
    const float* __restrict__ W1, const float* __restrict__ g1, const float* __restrict__ b1,
    const float* __restrict__ W2, const float* __restrict__ g2, const float* __restrict__ b2,
    const float* __restrict__ W3, const float* __restrict__ g3, const float* __restrict__ b3,
    float* __restrict__ out, float* __restrict__ ws)
{
    const int tid = threadIdx.x;
    const int bid = blockIdx.x;
    const int g = bid & 3;
    const int s = bid >> 2;          // 0..31 feature slice
    const int r0 = g * RPG;

    const int lane = tid & 63;
    const int wv   = tid >> 6;       // wave 0..7 (k-split)
    const int col  = lane & 15;
    const int kq   = lane >> 4;
    const int er   = tid >> 5;       // row 0..15 for elementwise phases
    const int l32  = tid & 31;

    float* a1    = ws + OFF_A1;
    float* a2    = ws + OFF_A2;
    float* oc_ws = ws + OFF_OC;
    float* of_ws = ws + OFF_OF;
    float* p3    = ws + OFF_P3;
    int* stb   = (int*)ws + OFF_ST;
    int* st_a1 = stb + 0   + g * 32;
    int* st_a2 = stb + 128 + g * 32;
    int* st_p3 = stb + 256 + g * 32;

    __shared__ __bf16 zh[16][776];   // x: bf16[0..255], c: bf16[256..767]
    __shared__ float comb[8][3][256];
    __shared__ float slab[16][48];   // raw o: [i|16+i|32+i] = h,c,f gates
    __shared__ float stats[16][2];
    __shared__ float g3c_s[512], b3c_s[512], g3f_s[512], b3f_s[512];

    // LN3 c/f params -> LDS (read per-col in the reconstruct pass)
    {
        g3c_s[tid] = g3[HDIM + tid];     b3c_s[tid] = b3[HDIM + tid];
        g3f_s[tid] = g3[2 * HDIM + tid]; b3f_s[tid] = b3[2 * HDIM + tid];
    }

    // ---------------- hoisted LN params (loop-invariant) ----------------
    float2 g1v[8], b1v[8], g2v[8], b2v[8];
    #pragma unroll
    for (int j = 0; j < 8; ++j) {
        int k = j * 64 + l32 * 2;
        g1v[j] = *(const float2*)(g1 + k); b1v[j] = *(const float2*)(b1 + k);
        g2v[j] = *(const float2*)(g2 + k); b2v[j] = *(const float2*)(b2 + k);
    }
    float g3h = 0.f, b3h = 0.f;
    if (tid < 256) {
        int i = tid & 15;
        g3h = g3[16 * s + i]; b3h = b3[16 * s + i];
    }

    // ---------------- weights -> register fragments (hi/lo split) ----------------
    bf16x8 w1h[3], w1l[3], w2h[2], w2l[2], w3h[3][2], w3l[3][2];
    #pragma unroll
    for (int ks = 0; ks < 3; ++ks) {
        int k0 = wv * 96 + ks * 32 + kq * 8;
        const float* p = W1 + (size_t)(16 * s + col) * K1 + k0;
        #pragma unroll
        for (int e = 0; e < 8; ++e) {
            bf16pair pr = split2(p[e]);
            w1h[ks][e] = pr.hi; w1l[ks][e] = pr.lo;
        }
    }
    #pragma unroll
    for (int ks = 0; ks < 2; ++ks) {
        int k0 = wv * 64 + ks * 32 + kq * 8;
        const float* p = W2 + (size_t)(16 * s + col) * HDIM + k0;
        #pragma unroll
        for (int e = 0; e < 8; ++e) {
            bf16pair pr = split2(p[e]);
            w2h[ks][e] = pr.hi; w2l[ks][e] = pr.lo;
        }
    }
    #pragma unroll
    for (int tb = 0; tb < 3; ++tb) {
        #pragma unroll
        for (int ks = 0; ks < 2; ++ks) {
            int k0 = wv * 64 + ks * 32 + kq * 8;
            const float* p = W3 + (size_t)(tb * HDIM + 16 * s + col) * HDIM + k0;
            #pragma unroll
            for (int e = 0; e < 8; ++e) {
                bf16pair pr = split2(p[e]);
                w3h[tb][ks][e] = pr.hi; w3l[tb][ks][e] = pr.lo;
            }
        }
    }

    // Reconstructed cell state: thread (er, l32) owns cols {2*l32+64k, +1}
    // of row r0+er, kept in f32 (recurrence in f32, closer to reference).
    float cr[8][2];
    #pragma unroll
    for (int k = 0; k < 8; ++k) { cr[k][0] = 0.f; cr[k][1] = 0.f; }

    // ---------------- prologue: zero c-region, write x(0), GEMM1-x(0) ----------------
    #pragma unroll
    for (int k = 0; k < 8; ++k)
        st_pair(&zh[er][256 + 2 * l32 + 64 * k], (__bf16)0.f, (__bf16)0.f);
    float2 xr[4];
    {
        const float* xrow = x + (size_t)(r0 + er) * IDIM;
        #pragma unroll
        for (int j = 0; j < 4; ++j) xr[j] = *(const float2*)(xrow + j * 64 + l32 * 2);
        unsigned* zrow = (unsigned*)&zh[er][0];
        #pragma unroll
        for (int j = 0; j < 4; ++j) zrow[j * 32 + l32] = pk2(xr[j].x, xr[j].y);
    }
    __syncthreads();
    f32x4 acc = {0.f, 0.f, 0.f, 0.f};
    #pragma unroll
    for (int ks = 0; ks < 3; ++ks) {
        int kb = wv * 96 + ks * 32;
        if (kb < IDIM) {
            bf16x8 ah = *(const bf16x8*)&zh[col][kb + kq * 8];
            acc = MFMA(ah, w1h[ks], acc);
            acc = MFMA(ah, w1l[ks], acc);
        }
    }

    #pragma unroll 1
    for (int t = 0; t < T_STEPS; ++t) {
        // ================= stage 1: GEMM1-c (x part already in acc) =================
        __syncthreads();                                              // B1
        #pragma unroll
        for (int ks = 0; ks < 3; ++ks) {
            int kb = wv * 96 + ks * 32;
            if (kb >= IDIM) {
                bf16x8 ah = *(const bf16x8*)&zh[col][kb + kq * 8];
                acc = MFMA(ah, w1h[ks], acc);
                acc = MFMA(ah, w1l[ks], acc);
            }
        }
        #pragma unroll
        for (int i = 0; i < 4; ++i) comb[wv][0][(kq * 4 + i) * 16 + col] = acc[i];
        __syncthreads();                                              // B2
        if (tid < 128) {
            int r = tid >> 3, fp = tid & 7;
            int i0 = r * 16 + fp * 2;
            float v0 = 0.f, v1 = 0.f;
            #pragma unroll
            for (int w = 0; w < 8; ++w) { v0 += comb[w][0][i0]; v1 += comb[w][0][i0 + 1]; }
            gstore2(&a1[(size_t)(r0 + r) * HDIM + 16 * s + fp * 2], v0, v1);
        }
        publish(&st_a1[s], t + 1);                                    // B3

        // ================= stage 2: h1 = elu(LN(a1)); GEMM2 =================
        poll_wave(st_a1, t + 1);
        {
            size_t arow = (size_t)(r0 + er) * HDIM;
            float2 va[8]; float s1 = 0.f, s2 = 0.f;
            #pragma unroll
            for (int j = 0; j < 8; ++j) {
                va[j] = gload2(a1 + arow + j * 64 + l32 * 2);
                s1 += va[j].x + va[j].y; s2 += va[j].x * va[j].x + va[j].y * va[j].y;
            }
            s1 += __shfl_xor(s1, 1, 64); s2 += __shfl_xor(s2, 1, 64);
            s1 += __shfl_xor(s1, 2, 64); s2 += __shfl_xor(s2, 2, 64);
            s1 += __shfl_xor(s1, 4, 64); s2 += __shfl_xor(s2, 4, 64);
            s1 += __shfl_xor(s1, 8, 64); s2 += __shfl_xor(s2, 8, 64);
            s1 += __shfl_xor(s1, 16, 64); s2 += __shfl_xor(s2, 16, 64);
            float mu = s1 * (1.f / HDIM);
            float var = s2 * (1.f / HDIM) - mu * mu;
            float rs = rsqrtf(var + 1e-5f);
            #pragma unroll
            for (int j = 0; j < 8; ++j) {
                int k = j * 64 + l32 * 2;
                float v0 = elu1((va[j].x - mu) * rs * g1v[j].x + b1v[j].x);
                float v1 = elu1((va[j].y - mu) * rs * g1v[j].y + b1v[j].y);
                st_pair(&zh[er][k], (__bf16)v0, (__bf16)v1);
            }
        }
        __syncthreads();                                              // B5
        {
            f32x4 acc2 = {0.f, 0.f, 0.f, 0.f};
            #pragma unroll
            for (int ks = 0; ks < 2; ++ks) {
                int k0 = wv * 64 + ks * 32 + kq * 8;
                bf16x8 ah = *(const bf16x8*)&zh[col][k0];
                acc2 = MFMA(ah, w2h[ks], acc2);
                acc2 = MFMA(ah, w2l[ks], acc2);
            }
            #pragma unroll
            for (int i = 0; i < 4; ++i) comb[wv][0][(kq * 4 + i) * 16 + col] = acc2[i];
        }
        __syncthreads();                                              // B6
        if (tid < 128) {
            int r = tid >> 3, fp = tid & 7;
            int i0 = r * 16 + fp * 2;
            float v0 = 0.f, v1 = 0.f;
            #pragma unroll
            for (int w = 0; w < 8; ++w) { v0 += comb[w][0][i0]; v1 += comb[w][0][i0 + 1]; }
            gstore2(&a2[(size_t)(r0 + r) * HDIM + 16 * s + fp * 2], v0, v1);
        }
        publish(&st_a2[s], t + 1);                                    // B7

        // ================= stage 3: h2 = elu(LN(a2)); prefetch x(t+1); GEMM3 =================
        poll_wave(st_a2, t + 1);
        {
            {   // prefetch next x while a2 loads are in flight
                int tn = (t + 1 < T_STEPS) ? t + 1 : t;
                const float* xrow = x + ((size_t)tn * BATCH + r0 + er) * IDIM;
                #pragma unroll
                for (int j = 0; j < 4; ++j) xr[j] = *(const float2*)(xrow + j * 64 + l32 * 2);
            }
            size_t arow = (size_t)(r0 + er) * HDIM;
            float2 va[8]; float s1 = 0.f, s2 = 0.f;
            #pragma unroll
            for (int j = 0; j < 8; ++j) va[j] = gload2(a2 + arow + j * 64 + l32 * 2);
            #pragma unroll
            for (int j = 0; j < 8; ++j) {
                s1 += va[j].x + va[j].y; s2 += va[j].x * va[j].x + va[j].y * va[j].y;
            }
            s1 += __shfl_xor(s1, 1, 64); s2 += __shfl_xor(s2, 1, 64);
            s1 += __shfl_xor(s1, 2, 64); s2 += __shfl_xor(s2, 2, 64);
            s1 += __shfl_xor(s1, 4, 64); s2 += __shfl_xor(s2, 4, 64);
            s1 += __shfl_xor(s1, 8, 64); s2 += __shfl_xor(s2, 8, 64);
            s1 += __shfl_xor(s1, 16, 64); s2 += __shfl_xor(s2, 16, 64);
            float mu = s1 * (1.f / HDIM);
            float var = s2 * (1.f / HDIM) - mu * mu;
            float rs = rsqrtf(var + 1e-5f);
            #pragma unroll
            for (int j = 0; j < 8; ++j) {
                int k = j * 64 + l32 * 2;
                float v0 = elu1((va[j].x - mu) * rs * g2v[j].x + b2v[j].x);
                float v1 = elu1((va[j].y - mu) * rs * g2v[j].y + b2v[j].y);
                st_pair(&zh[er][k], (__bf16)v0, (__bf16)v1);
            }
        }
        __syncthreads();                                              // B8
        {
            f32x4 acc0 = {0.f,0.f,0.f,0.f}, acc1 = {0.f,0.f,0.f,0.f}, acc2 = {0.f,0.f,0.f,0.f};
            #pragma unroll
            for (int ks = 0; ks < 2; ++ks) {
                int k0 = wv * 64 + ks * 32 + kq * 8;
                bf16x8 ah = *(const bf16x8*)&zh[col][k0];
                acc0 = MFMA(ah, w3h[0][ks], acc0);
                acc0 = MFMA(ah, w3l[0][ks], acc0);
                acc1 = MFMA(ah, w3h[1][ks], acc1);
                acc1 = MFMA(ah, w3l[1][ks], acc1);
                acc2 = MFMA(ah, w3h[2][ks], acc2);
                acc2 = MFMA(ah, w3l[2][ks], acc2);
            }
            #pragma unroll
            for (int i = 0; i < 4; ++i) {
                comb[wv][0][(kq * 4 + i) * 16 + col] = acc0[i];
                comb[wv][1][(kq * 4 + i) * 16 + col] = acc1[i];
                comb[wv][2][(kq * 4 + i) * 16 + col] = acc2[i];
            }
        }
        __syncthreads();                                              // B9
        if (tid < 384) {             // reduce; broadcast raw o_c / o_f slices
            int o = tid * 2;
            int tb = o >> 8, idx = o & 255;
            int r = idx >> 4, f0 = idx & 15;
            float v0 = 0.f, v1 = 0.f;
            #pragma unroll
            for (int w = 0; w < 8; ++w) { v0 += comb[w][tb][idx]; v1 += comb[w][tb][idx + 1]; }
            slab[r][tb * 16 + f0]     = v0;
            slab[r][tb * 16 + f0 + 1] = v1;
            if (tb == 1)
                gstore2(&oc_ws[(size_t)(r0 + r) * HDIM + 16 * s + f0], v0, v1);
            else if (tb == 2)
                gstore2(&of_ws[(size_t)(r0 + r) * HDIM + 16 * s + f0], v0, v1);
        }
        {   // x(t+1) -> zh x-region (GEMM3 done with it at B9)
            unsigned* zrow = (unsigned*)&zh[er][0];
            #pragma unroll
            for (int j = 0; j < 4; ++j) zrow[j * 32 + l32] = pk2(xr[j].x, xr[j].y);
        }
        __syncthreads();                                              // B10
        {
            float va_ = slab[er][l32];
            float vb_ = (l32 < 16) ? slab[er][32 + l32] : 0.f;
            float s1 = va_ + vb_;
            float s2 = va_ * va_ + vb_ * vb_;
            s1 += __shfl_xor(s1, 1, 64); s2 += __shfl_xor(s2, 1, 64);
            s1 += __shfl_xor(s1, 2, 64); s2 += __shfl_xor(s2, 2, 64);
            s1 += __shfl_xor(s1, 4, 64); s2 += __shfl_xor(s2, 4, 64);
            s1 += __shfl_xor(s1, 8, 64); s2 += __shfl_xor(s2, 8, 64);
            s1 += __shfl_xor(s1, 16, 64); s2 += __shfl_xor(s2, 16, 64);
            if (l32 == 0) gstore2(&p3[((size_t)(r0 + er) * NSLICE + s) * 2], s1, s2);
        }
        publish(&st_p3[s], t + 1);                                    // B11

        // -------- hoisted GEMM1-x for t+1: hidden inside the p3 RT window --------
        acc[0] = 0.f; acc[1] = 0.f; acc[2] = 0.f; acc[3] = 0.f;
        #pragma unroll
        for (int ks = 0; ks < 3; ++ks) {
            int kb = wv * 96 + ks * 32;
            if (kb < IDIM) {
                bf16x8 ah = *(const bf16x8*)&zh[col][kb + kq * 8];
                acc = MFMA(ah, w1h[ks], acc);
                acc = MFMA(ah, w1l[ks], acc);
            }
        }

        // ================= epilogue: LN3 stats; h out; reconstruct full c =================
        poll_wave(st_p3, t + 1);
        // issue o_c / o_f gathers first (overlap with the stats reduce)
        float2 ocv[8], ofv[8];
        {
            const float* ocr = oc_ws + (size_t)(r0 + er) * HDIM + 2 * l32;
            const float* ofr = of_ws + (size_t)(r0 + er) * HDIM + 2 * l32;
            #pragma unroll
            for (int k = 0; k < 8; ++k) {
                ocv[k] = gload2(ocr + 64 * k);
                ofv[k] = gload2(ofr + 64 * k);
            }
        }
        {
            float2 pv = gload2(&p3[((size_t)(r0 + er) * NSLICE + l32) * 2]);
            float s1 = pv.x, s2 = pv.y;
            s1 += __shfl_xor(s1, 1, 64); s2 += __shfl_xor(s2, 1, 64);
            s1 += __shfl_xor(s1, 2, 64); s2 += __shfl_xor(s2, 2, 64);
            s1 += __shfl_xor(s1, 4, 64); s2 += __shfl_xor(s2, 4, 64);
            s1 += __shfl_xor(s1, 8, 64); s2 += __shfl_xor(s2, 8, 64);
            s1 += __shfl_xor(s1, 16, 64); s2 += __shfl_xor(s2, 16, 64);
            float mu = s1 * (1.f / H3);
            float var = s2 * (1.f / H3) - mu * mu;
            float rs = rsqrtf(var + 1e-5f);
            if (l32 == 0) { stats[er][0] = mu; stats[er][1] = rs; }
        }
        __syncthreads();                                              // B12
        if (tid < 256) {             // own-slice h output FIRST (drain overlaps c-loop)
            int r = tid >> 4, i = tid & 15;
            float mu = stats[r][0], rs = stats[r][1];
            float oh = (slab[r][i] - mu) * rs * g3h + b3h;
            out[((size_t)t * BATCH + r0 + r) * HDIM + 16 * s + i] = elu1(oh);
        }
        {
            float mu = stats[er][0], rs = stats[er][1];
            #pragma unroll
            for (int k = 0; k < 8; ++k) {
                int c0k = 2 * l32 + 64 * k;
                float2 gc = *(const float2*)&g3c_s[c0k];
                float2 bc = *(const float2*)&b3c_s[c0k];
                float2 gf = *(const float2*)&g3f_s[c0k];
                float2 bf = *(const float2*)&b3f_s[c0k];
                float ocn0 = (ocv[k].x - mu) * rs * gc.x + bc.x;
                float ocn1 = (ocv[k].y - mu) * rs * gc.y + bc.y;
                float ofn0 = (ofv[k].x - mu) * rs * gf.x + bf.x;
                float ofn1 = (ofv[k].y - mu) * rs * gf.y + bf.y;
                float sg0 = 1.f / (1.f + expf(-ofn0)); float f0 = sg0 * sg0;
                float sg1 = 1.f / (1.f + expf(-ofn1)); float f1 = sg1 * sg1;
                float cn0 = f0 * elu1(ocn0) + (1.f - f0) * cr[k][0];
                float cn1 = f1 * elu1(ocn1) + (1.f - f1) * cr[k][1];
                cr[k][0] = cn0; cr[k][1] = cn1;
                st_pair(&zh[er][256 + c0k], (__bf16)cn0, (__bf16)cn1);
                if (t == T_STEPS - 1 && s == 0) {
                    float2 cf = {cn0, cn1};
                    *(float2*)(out + (size_t)T_STEPS * BATCH * HDIM
                                   + (size_t)(r0 + er) * HDIM + c0k) = cf;
                }
            }
        }
        // loop top B1 orders zh c-writes before next GEMM1-c reads
    }
}

extern "C" void kernel_launch(void* const* d_in, const int* in_sizes, int n_in,
                              void* d_out, int out_size, void* d_ws, size_t ws_size,
                              hipStream_t stream) {
    const float* x  = (const float*)d_in[0];
    const float* W1 = (const float*)d_in[1];
    const float* g1 = (const float*)d_in[2];
    const float* b1 = (const float*)d_in[3];
    const float* W2 = (const float*)d_in[4];
    const float* g2 = (const float*)d_in[5];
    const float* b2 = (const float*)d_in[6];
    const float* W3 = (const float*)d_in[7];
    const float* g3 = (const float*)d_in[8];
    const float* b3 = (const float*)d_in[9];
    float* out = (float*)d_out;
    float* ws  = (float*)d_ws;

    dlstm_init<<<1, 512, 0, stream>>>(ws);
    dlstm_main<<<NGROUP * NSLICE, THREADS, 0, stream>>>(x, W1, g1, b1, W2, g2, b2, W3, g3, b3, out, ws);
}